// Round 2
// baseline (554.811 us; speedup 1.0000x reference)
//
#include <hip/hip_runtime.h>

// Problem constants (fixed by reference setup_inputs)
#define NN 100000
#define NE 1600000

typedef unsigned int uint;
typedef unsigned short ushort;

__device__ __forceinline__ float blo(uint u){ return __uint_as_float(u << 16); }
__device__ __forceinline__ float bhi(uint u){ return __uint_as_float(u & 0xffff0000u); }
__device__ __forceinline__ float b2f(ushort u){ return __uint_as_float(((uint)u) << 16); }
__device__ __forceinline__ ushort f2b(float f){
  uint u = __float_as_uint(f);
  uint r = (u + 0x7fffu + ((u >> 16) & 1u)) >> 16;
  return (ushort)r;
}
// load float element i from a buffer that is bf16 (isb) or f32
__device__ __forceinline__ float ldf(const void* p, int i, bool isb){
  return isb ? b2f(((const ushort*)p)[i]) : ((const float*)p)[i];
}

// ---------------------------------------------------------------------------
// prep: probe dtypes, convert weights to f32 combined tables
// flags[0] = 1 if float tensors are bf16, 0 if f32
// flags[1] = 1 if edge_index buffer is int64-layout, 0 if int32
// wc1[64][64]: cols 0..31 = W_self1, cols 32..63 = W_neigh1
// wc2[32][64]: cols 0..31 = W_self2, cols 32..63 = W_neigh2
// ---------------------------------------------------------------------------
__global__ void prep_k(const uint* __restrict__ xw,  const int* __restrict__ ei,
                       const void* __restrict__ Ws1, const void* __restrict__ bs1,
                       const void* __restrict__ Wn1, const void* __restrict__ bn1,
                       const void* __restrict__ Ws2, const void* __restrict__ bs2,
                       const void* __restrict__ Wn2, const void* __restrict__ bn2,
                       const void* __restrict__ Wo,  const void* __restrict__ bo,
                       float* __restrict__ wc1, float* __restrict__ bc1,
                       float* __restrict__ wc2, float* __restrict__ bc2,
                       float* __restrict__ wof, float* __restrict__ bof,
                       float* __restrict__ bn1f, float* __restrict__ bn2f,
                       int* __restrict__ flags)
{
  int t = threadIdx.x; // one block, 256 threads
  __shared__ int nz, bcnt;
  __shared__ int s_isb, s_ei64;
  if (t == 0) { nz = 0; bcnt = 0; }
  __syncthreads();

  // --- edge layout probe: int64 little-endian => every odd int32 word is 0
  int hiw = ei[2 * t + 1];
  if (hiw != 0) atomicOr(&nz, 1);

  // --- float dtype probe: bits[14:7] of each uint32 word are the low
  // element's bf16 exponent field if packed-bf16 (concentrated ~[96,144]);
  // uniform-random mantissa bits if f32.
  uint u = xw[t];
  uint le = (u >> 7) & 0xFFu;
  if (le == 0u || (le >= 96u && le <= 144u)) atomicAdd(&bcnt, 1);
  __syncthreads();
  if (t == 0) {
    s_ei64 = (nz == 0) ? 1 : 0;
    s_isb  = (bcnt >= 240) ? 1 : 0;
    flags[0] = s_isb;
    flags[1] = s_ei64;
  }
  __syncthreads();
  bool isb = (s_isb != 0);

  for (int i = t; i < 64 * 64; i += 256) {
    int f = i >> 6, j = i & 63;
    wc1[i] = (j < 32) ? ldf(Ws1, f * 32 + j, isb) : ldf(Wn1, f * 32 + (j - 32), isb);
  }
  for (int i = t; i < 64; i += 256) bc1[i] = (i < 32) ? ldf(bs1, i, isb) : 0.f;
  for (int i = t; i < 32 * 64; i += 256) {
    int f = i >> 6, j = i & 63;
    wc2[i] = (j < 32) ? ldf(Ws2, f * 32 + j, isb) : ldf(Wn2, f * 32 + (j - 32), isb);
  }
  for (int i = t; i < 64; i += 256) bc2[i] = (i < 32) ? ldf(bs2, i, isb) : 0.f;
  for (int i = t; i < 32 * 40; i += 256) wof[i] = ldf(Wo, i, isb);
  for (int i = t; i < 40; i += 256) bof[i] = ldf(bo, i, isb);
  for (int i = t; i < 32; i += 256) bn1f[i] = ldf(bn1, i, isb);
  for (int i = t; i < 32; i += 256) bn2f[i] = ldf(bn2, i, isb);
}

// ---------------------------------------------------------------------------
// CSR build
// ---------------------------------------------------------------------------
__global__ void count_k(const int* __restrict__ ei, int* __restrict__ deg,
                        const int* __restrict__ flags, int E)
{
  int e = blockIdx.x * 256 + threadIdx.x;
  if (e >= E) return;
  int m = flags[1];
  int d = m ? ei[2 * (E + e)] : ei[E + e];
  atomicAdd(&deg[d], 1);
}

__global__ void scan_partials_k(const int* __restrict__ deg, int* __restrict__ bsum, int N)
{
  __shared__ int sm[256];
  int b = blockIdx.x, t = threadIdx.x;
  int base = b * 1024 + t * 4;
  int s = 0;
#pragma unroll
  for (int k = 0; k < 4; k++) { int i = base + k; if (i < N) s += deg[i]; }
  sm[t] = s;
  __syncthreads();
  for (int off = 128; off > 0; off >>= 1) {
    if (t < off) sm[t] += sm[t + off];
    __syncthreads();
  }
  if (t == 0) bsum[b] = sm[0];
}

__global__ void scan_bsum_k(int* __restrict__ bsum, int NB)
{
  __shared__ int sm[128];
  int t = threadIdx.x;
  int orig = (t < NB) ? bsum[t] : 0;
  sm[t] = orig;
  __syncthreads();
  for (int off = 1; off < 128; off <<= 1) {
    int v = (t >= off) ? sm[t - off] : 0;
    __syncthreads();
    sm[t] += v;
    __syncthreads();
  }
  if (t < NB) bsum[t] = sm[t] - orig; // exclusive
}

__global__ void scan_apply_k(const int* __restrict__ deg, const int* __restrict__ bsum,
                             int* __restrict__ rowptr, int* __restrict__ cursor, int N, int E)
{
  __shared__ int sm[256];
  int b = blockIdx.x, t = threadIdx.x;
  int base = b * 1024 + t * 4;
  int v[4]; int s = 0;
#pragma unroll
  for (int k = 0; k < 4; k++) { int i = base + k; v[k] = (i < N) ? deg[i] : 0; s += v[k]; }
  sm[t] = s;
  __syncthreads();
  for (int off = 1; off < 256; off <<= 1) {
    int x = (t >= off) ? sm[t - off] : 0;
    __syncthreads();
    sm[t] += x;
    __syncthreads();
  }
  int excl = sm[t] - s + bsum[b];
#pragma unroll
  for (int k = 0; k < 4; k++) {
    int i = base + k;
    if (i < N) { rowptr[i] = excl; cursor[i] = excl; }
    excl += v[k];
  }
  if (b == 0 && t == 0) rowptr[N] = E;
}

__global__ void fill_k(const int* __restrict__ ei, int* __restrict__ cursor,
                       int* __restrict__ col, const int* __restrict__ flags, int E)
{
  int e = blockIdx.x * 256 + threadIdx.x;
  if (e >= E) return;
  int m = flags[1];
  int s = m ? ei[2 * e] : ei[e];
  int d = m ? ei[2 * (E + e)] : ei[E + e];
  int p = atomicAdd(&cursor[d], 1);
  col[p] = s;
}

// ---------------------------------------------------------------------------
// Dense transform: thread-per-node, weights via uniform (scalar) loads.
// XDYN: input dtype chosen at runtime by flags[0] (bf16 vs f32); else f32.
// ODYN: output dtype chosen at runtime by flags[0]; else f32 (tbuf).
// eoff: element offset into xout (for the logits region of d_out).
// ---------------------------------------------------------------------------
template <int IN, int OUT, int CHUNK, bool XDYN, bool ODYN>
__global__ __launch_bounds__(256) void transform_k(const void* __restrict__ xin,
                                                   const float* __restrict__ W,
                                                   const float* __restrict__ bias,
                                                   void* __restrict__ xout,
                                                   const int* __restrict__ flags,
                                                   long long eoff, int N)
{
  int n = blockIdx.x * 256 + threadIdx.x;
  if (n >= N) return;
  bool isb = (XDYN || ODYN) ? (flags[0] != 0) : false;
  float xr[IN];
  if (XDYN && isb) {
    const uint4* p = (const uint4*)((const ushort*)xin + (size_t)n * IN);
#pragma unroll
    for (int k = 0; k < IN / 8; k++) {
      uint4 v = p[k];
      xr[8 * k + 0] = blo(v.x); xr[8 * k + 1] = bhi(v.x);
      xr[8 * k + 2] = blo(v.y); xr[8 * k + 3] = bhi(v.y);
      xr[8 * k + 4] = blo(v.z); xr[8 * k + 5] = bhi(v.z);
      xr[8 * k + 6] = blo(v.w); xr[8 * k + 7] = bhi(v.w);
    }
  } else {
    const float4* p = (const float4*)((const float*)xin + (size_t)n * IN);
#pragma unroll
    for (int k = 0; k < IN / 4; k++) {
      float4 v = p[k];
      xr[4 * k + 0] = v.x; xr[4 * k + 1] = v.y; xr[4 * k + 2] = v.z; xr[4 * k + 3] = v.w;
    }
  }
#pragma unroll 1
  for (int j0 = 0; j0 < OUT; j0 += CHUNK) {
    float acc[CHUNK];
#pragma unroll
    for (int jj = 0; jj < CHUNK; jj++) acc[jj] = bias[j0 + jj];
#pragma unroll 8
    for (int f = 0; f < IN; f++) {
      float xv = xr[f];
#pragma unroll
      for (int jj = 0; jj < CHUNK; jj++)
        acc[jj] = fmaf(xv, W[f * OUT + j0 + jj], acc[jj]);
    }
    if (ODYN && isb) {
      uint* o = (uint*)((ushort*)xout + eoff + (size_t)n * OUT + j0);
#pragma unroll
      for (int q = 0; q < CHUNK / 2; q++)
        o[q] = (uint)f2b(acc[2 * q]) | ((uint)f2b(acc[2 * q + 1]) << 16);
    } else {
      float* o = (float*)xout + eoff + (size_t)n * OUT + j0;
#pragma unroll
      for (int q = 0; q < CHUNK / 4; q++)
        ((float4*)o)[q] = make_float4(acc[4 * q], acc[4 * q + 1], acc[4 * q + 2], acc[4 * q + 3]);
    }
  }
}

// ---------------------------------------------------------------------------
// Aggregation: wave-per-node, lanes 0..31 = feats, two neighbors in flight.
// t rows are [N][64]: self part at +0, neigh part at +32.
// hout[d] = relu(mean_neigh + b_neigh + self); optional mirror into d_out
// (x32 output) with dtype chosen by flags[0].
// ---------------------------------------------------------------------------
__global__ __launch_bounds__(256) void aggregate_k(const float* __restrict__ t,
                                                   const int* __restrict__ rowptr,
                                                   const int* __restrict__ col,
                                                   const float* __restrict__ bneigh,
                                                   float* __restrict__ hout,
                                                   void* __restrict__ out2,
                                                   const int* __restrict__ flags, int N)
{
  int d = blockIdx.x * 4 + (threadIdx.x >> 6);
  if (d >= N) return;
  int lane = threadIdx.x & 63;
  int half = lane >> 5, f = lane & 31;
  int start = rowptr[d], end = rowptr[d + 1];
  float acc = 0.f;
  for (int e = start + half; e < end; e += 2)
    acc += t[(size_t)col[e] * 64 + 32 + f];
  acc += __shfl_down(acc, 32, 64);
  if (lane < 32) {
    int deg = end - start;
    float scale = 1.0f / (float)max(deg, 1);
    float v = fmaf(acc, scale, bneigh[f] + t[(size_t)d * 64 + f]);
    v = fmaxf(v, 0.f);
    hout[(size_t)d * 32 + f] = v;
    if (out2) {
      if (flags[0] != 0) ((ushort*)out2)[(size_t)d * 32 + f] = f2b(v);
      else               ((float*)out2)[(size_t)d * 32 + f] = v;
    }
  }
}

// ---------------------------------------------------------------------------
extern "C" void kernel_launch(void* const* d_in, const int* in_sizes, int n_in,
                              void* d_out, int out_size, void* d_ws, size_t ws_size,
                              hipStream_t stream)
{
  const int N = NN, E = NE;
  const void* x   = d_in[0];
  const int*  ei  = (const int*)d_in[1];

  char* p = (char*)d_ws;
  auto alloc = [&](size_t bytes) -> void* {
    void* r = (void*)p;
    p += (bytes + 255) & ~(size_t)255;
    return r;
  };
  float* wc1  = (float*)alloc(64 * 64 * 4);
  float* bc1  = (float*)alloc(64 * 4);
  float* wc2  = (float*)alloc(32 * 64 * 4);
  float* bc2  = (float*)alloc(64 * 4);
  float* wof  = (float*)alloc(32 * 40 * 4);
  float* bof  = (float*)alloc(40 * 4);
  float* bn1f = (float*)alloc(32 * 4);
  float* bn2f = (float*)alloc(32 * 4);
  int*   flags = (int*)alloc(8);
  int*   deg  = (int*)alloc((size_t)N * 4);
  int*   rowptr = (int*)alloc(((size_t)N + 1) * 4);
  int*   cursor = (int*)alloc((size_t)N * 4);
  int*   bsum = (int*)alloc(512 * 4);
  int*   col  = (int*)alloc((size_t)E * 4);
  float* tbuf = (float*)alloc((size_t)N * 64 * 4); // t1 / t2 (aliased)
  float* hbuf = (float*)alloc((size_t)N * 32 * 4); // h1 / h2 (aliased)

  const int NB = (N + 1023) / 1024; // 98

  prep_k<<<1, 256, 0, stream>>>((const uint*)x, ei,
                                d_in[2], d_in[3], d_in[4], d_in[5],
                                d_in[6], d_in[7], d_in[8], d_in[9],
                                d_in[10], d_in[11],
                                wc1, bc1, wc2, bc2, wof, bof, bn1f, bn2f, flags);
  hipMemsetAsync(deg, 0, (size_t)N * 4, stream);
  count_k<<<(E + 255) / 256, 256, 0, stream>>>(ei, deg, flags, E);
  scan_partials_k<<<NB, 256, 0, stream>>>(deg, bsum, N);
  scan_bsum_k<<<1, 128, 0, stream>>>(bsum, NB);
  scan_apply_k<<<NB, 256, 0, stream>>>(deg, bsum, rowptr, cursor, N, E);
  fill_k<<<(E + 255) / 256, 256, 0, stream>>>(ei, cursor, col, flags, E);

  // Layer 1: t1 = [x@Ws1+bs1 | x@Wn1], aggregate -> h1
  transform_k<64, 64, 32, true, false><<<(N + 255) / 256, 256, 0, stream>>>(
      x, wc1, bc1, tbuf, flags, 0LL, N);
  aggregate_k<<<(N + 3) / 4, 256, 0, stream>>>(tbuf, rowptr, col, bn1f, hbuf,
                                               (void*)nullptr, flags, N);

  // Layer 2: t2 = [h1@Ws2+bs2 | h1@Wn2], aggregate -> h2 (+x32 output)
  transform_k<32, 64, 64, false, false><<<(N + 255) / 256, 256, 0, stream>>>(
      hbuf, wc2, bc2, tbuf, flags, 0LL, N);
  aggregate_k<<<(N + 3) / 4, 256, 0, stream>>>(tbuf, rowptr, col, bn2f, hbuf,
                                               d_out, flags, N);

  // Output head: logits = h2@Wo + bo -> d_out at element offset N*32
  transform_k<32, 40, 40, false, true><<<(N + 255) / 256, 256, 0, stream>>>(
      hbuf, wof, bof, d_out, flags, (long long)N * 32, N);
}

// Round 3
// 497.584 us; speedup vs baseline: 1.1150x; 1.1150x over previous
//
#include <hip/hip_runtime.h>

// Problem constants (fixed by reference setup_inputs)
#define NN 100000
#define NE 1600000
#define NPR 12500  // nodes per XCD range (NN/8)

typedef unsigned int uint;
typedef unsigned short ushort;

__device__ __forceinline__ float blo(uint u){ return __uint_as_float(u << 16); }
__device__ __forceinline__ float bhi(uint u){ return __uint_as_float(u & 0xffff0000u); }
__device__ __forceinline__ float b2f(ushort u){ return __uint_as_float(((uint)u) << 16); }
__device__ __forceinline__ ushort f2b(float f){
  uint u = __float_as_uint(f);
  uint r = (u + 0x7fffu + ((u >> 16) & 1u)) >> 16;
  return (ushort)r;
}
// load float element i from a buffer that is bf16 (isb) or f32
__device__ __forceinline__ float ldf(const void* p, int i, bool isb){
  return isb ? b2f(((const ushort*)p)[i]) : ((const float*)p)[i];
}

// ---------------------------------------------------------------------------
// prep: probe dtypes, convert weights to f32 combined tables
// flags[0] = 1 if float tensors are bf16, 0 if f32
// flags[1] = 1 if edge_index buffer is int64-layout, 0 if int32
// ---------------------------------------------------------------------------
__global__ void prep_k(const uint* __restrict__ xw,  const int* __restrict__ ei,
                       const void* __restrict__ Ws1, const void* __restrict__ bs1,
                       const void* __restrict__ Wn1, const void* __restrict__ bn1,
                       const void* __restrict__ Ws2, const void* __restrict__ bs2,
                       const void* __restrict__ Wn2, const void* __restrict__ bn2,
                       const void* __restrict__ Wo,  const void* __restrict__ bo,
                       float* __restrict__ wc1, float* __restrict__ bc1,
                       float* __restrict__ wc2, float* __restrict__ bc2,
                       float* __restrict__ wof, float* __restrict__ bof,
                       float* __restrict__ bn1f, float* __restrict__ bn2f,
                       int* __restrict__ flags)
{
  int t = threadIdx.x; // one block, 256 threads
  __shared__ int nz, bcnt;
  __shared__ int s_isb, s_ei64;
  if (t == 0) { nz = 0; bcnt = 0; }
  __syncthreads();

  // --- edge layout probe: int64 little-endian => every odd int32 word is 0
  int hiw = ei[2 * t + 1];
  if (hiw != 0) atomicOr(&nz, 1);

  // --- float dtype probe: bits[14:7] of each uint32 word are the low
  // element's bf16 exponent field if packed-bf16 (concentrated ~[96,144]);
  // uniform-random mantissa bits if f32.
  uint u = xw[t];
  uint le = (u >> 7) & 0xFFu;
  if (le == 0u || (le >= 96u && le <= 144u)) atomicAdd(&bcnt, 1);
  __syncthreads();
  if (t == 0) {
    s_ei64 = (nz == 0) ? 1 : 0;
    s_isb  = (bcnt >= 240) ? 1 : 0;
    flags[0] = s_isb;
    flags[1] = s_ei64;
  }
  __syncthreads();
  bool isb = (s_isb != 0);

  for (int i = t; i < 64 * 64; i += 256) {
    int f = i >> 6, j = i & 63;
    wc1[i] = (j < 32) ? ldf(Ws1, f * 32 + j, isb) : ldf(Wn1, f * 32 + (j - 32), isb);
  }
  for (int i = t; i < 64; i += 256) bc1[i] = (i < 32) ? ldf(bs1, i, isb) : 0.f;
  for (int i = t; i < 32 * 64; i += 256) {
    int f = i >> 6, j = i & 63;
    wc2[i] = (j < 32) ? ldf(Ws2, f * 32 + j, isb) : ldf(Wn2, f * 32 + (j - 32), isb);
  }
  for (int i = t; i < 64; i += 256) bc2[i] = (i < 32) ? ldf(bs2, i, isb) : 0.f;
  for (int i = t; i < 32 * 40; i += 256) wof[i] = ldf(Wo, i, isb);
  for (int i = t; i < 40; i += 256) bof[i] = ldf(bo, i, isb);
  for (int i = t; i < 32; i += 256) bn1f[i] = ldf(bn1, i, isb);
  for (int i = t; i < 32; i += 256) bn2f[i] = ldf(bn2, i, isb);
}

// ---------------------------------------------------------------------------
// CSR build — XCD-partitioned scatter.
// blockIdx%8 -> XCD (round-robin heuristic); each XCD owns a 12.5K-dst range,
// so its cursor slice (50KB) + col slice (~800KB) stay resident in its 4MiB
// L2: atomics and scattered stores never cross XCDs, lines fill completely
// before eviction. Edge list (LLC-resident) is streamed 8x — cheap reads
// traded for localized writes.
// ---------------------------------------------------------------------------
__global__ __launch_bounds__(256) void count_k(const int* __restrict__ ei,
                                               int* __restrict__ deg,
                                               const int* __restrict__ flags, int E)
{
  int r = blockIdx.x & 7;
  int grp = blockIdx.x >> 3;
  int nb = gridDim.x >> 3;
  int m = flags[1];
  int lo = r * NPR, hi = lo + NPR;
  for (int e = grp * 256 + threadIdx.x; e < E; e += nb * 256) {
    int d = m ? ei[2 * (E + e)] : ei[E + e];
    if (d >= lo && d < hi) atomicAdd(&deg[d], 1);
  }
}

__global__ void scan_partials_k(const int* __restrict__ deg, int* __restrict__ bsum, int N)
{
  __shared__ int sm[256];
  int b = blockIdx.x, t = threadIdx.x;
  int base = b * 1024 + t * 4;
  int s = 0;
#pragma unroll
  for (int k = 0; k < 4; k++) { int i = base + k; if (i < N) s += deg[i]; }
  sm[t] = s;
  __syncthreads();
  for (int off = 128; off > 0; off >>= 1) {
    if (t < off) sm[t] += sm[t + off];
    __syncthreads();
  }
  if (t == 0) bsum[b] = sm[0];
}

__global__ void scan_bsum_k(int* __restrict__ bsum, int NB)
{
  __shared__ int sm[128];
  int t = threadIdx.x;
  int orig = (t < NB) ? bsum[t] : 0;
  sm[t] = orig;
  __syncthreads();
  for (int off = 1; off < 128; off <<= 1) {
    int v = (t >= off) ? sm[t - off] : 0;
    __syncthreads();
    sm[t] += v;
    __syncthreads();
  }
  if (t < NB) bsum[t] = sm[t] - orig; // exclusive
}

__global__ void scan_apply_k(const int* __restrict__ deg, const int* __restrict__ bsum,
                             int* __restrict__ rowptr, int* __restrict__ cursor, int N, int E)
{
  __shared__ int sm[256];
  int b = blockIdx.x, t = threadIdx.x;
  int base = b * 1024 + t * 4;
  int v[4]; int s = 0;
#pragma unroll
  for (int k = 0; k < 4; k++) { int i = base + k; v[k] = (i < N) ? deg[i] : 0; s += v[k]; }
  sm[t] = s;
  __syncthreads();
  for (int off = 1; off < 256; off <<= 1) {
    int x = (t >= off) ? sm[t - off] : 0;
    __syncthreads();
    sm[t] += x;
    __syncthreads();
  }
  int excl = sm[t] - s + bsum[b];
#pragma unroll
  for (int k = 0; k < 4; k++) {
    int i = base + k;
    if (i < N) { rowptr[i] = excl; cursor[i] = excl; }
    excl += v[k];
  }
  if (b == 0 && t == 0) rowptr[N] = E;
}

__global__ __launch_bounds__(256) void fill_k(const int* __restrict__ ei,
                                              int* __restrict__ cursor,
                                              int* __restrict__ col,
                                              const int* __restrict__ flags, int E)
{
  int r = blockIdx.x & 7;
  int grp = blockIdx.x >> 3;
  int nb = gridDim.x >> 3;
  int m = flags[1];
  int lo = r * NPR, hi = lo + NPR;
  for (int e = grp * 256 + threadIdx.x; e < E; e += nb * 256) {
    int d = m ? ei[2 * (E + e)] : ei[E + e];
    if (d >= lo && d < hi) {
      int s = m ? ei[2 * e] : ei[e];
      int p = atomicAdd(&cursor[d], 1);
      col[p] = s;
    }
  }
}

// ---------------------------------------------------------------------------
// Dense transform: thread-per-node, weights via uniform (scalar) loads.
// ---------------------------------------------------------------------------
template <int IN, int OUT, int CHUNK, bool XDYN, bool ODYN>
__global__ __launch_bounds__(256) void transform_k(const void* __restrict__ xin,
                                                   const float* __restrict__ W,
                                                   const float* __restrict__ bias,
                                                   void* __restrict__ xout,
                                                   const int* __restrict__ flags,
                                                   long long eoff, int N)
{
  int n = blockIdx.x * 256 + threadIdx.x;
  if (n >= N) return;
  bool isb = (XDYN || ODYN) ? (flags[0] != 0) : false;
  float xr[IN];
  if (XDYN && isb) {
    const uint4* p = (const uint4*)((const ushort*)xin + (size_t)n * IN);
#pragma unroll
    for (int k = 0; k < IN / 8; k++) {
      uint4 v = p[k];
      xr[8 * k + 0] = blo(v.x); xr[8 * k + 1] = bhi(v.x);
      xr[8 * k + 2] = blo(v.y); xr[8 * k + 3] = bhi(v.y);
      xr[8 * k + 4] = blo(v.z); xr[8 * k + 5] = bhi(v.z);
      xr[8 * k + 6] = blo(v.w); xr[8 * k + 7] = bhi(v.w);
    }
  } else {
    const float4* p = (const float4*)((const float*)xin + (size_t)n * IN);
#pragma unroll
    for (int k = 0; k < IN / 4; k++) {
      float4 v = p[k];
      xr[4 * k + 0] = v.x; xr[4 * k + 1] = v.y; xr[4 * k + 2] = v.z; xr[4 * k + 3] = v.w;
    }
  }
#pragma unroll 1
  for (int j0 = 0; j0 < OUT; j0 += CHUNK) {
    float acc[CHUNK];
#pragma unroll
    for (int jj = 0; jj < CHUNK; jj++) acc[jj] = bias[j0 + jj];
#pragma unroll 8
    for (int f = 0; f < IN; f++) {
      float xv = xr[f];
#pragma unroll
      for (int jj = 0; jj < CHUNK; jj++)
        acc[jj] = fmaf(xv, W[f * OUT + j0 + jj], acc[jj]);
    }
    if (ODYN && isb) {
      uint* o = (uint*)((ushort*)xout + eoff + (size_t)n * OUT + j0);
#pragma unroll
      for (int q = 0; q < CHUNK / 2; q++)
        o[q] = (uint)f2b(acc[2 * q]) | ((uint)f2b(acc[2 * q + 1]) << 16);
    } else {
      float* o = (float*)xout + eoff + (size_t)n * OUT + j0;
#pragma unroll
      for (int q = 0; q < CHUNK / 4; q++)
        ((float4*)o)[q] = make_float4(acc[4 * q], acc[4 * q + 1], acc[4 * q + 2], acc[4 * q + 3]);
    }
  }
}

// ---------------------------------------------------------------------------
// Aggregation: wave-per-node, lanes 0..31 = feats, two neighbors in flight.
// t rows are [N][64]: self part at +0, neigh part at +32.
// ---------------------------------------------------------------------------
__global__ __launch_bounds__(256) void aggregate_k(const float* __restrict__ t,
                                                   const int* __restrict__ rowptr,
                                                   const int* __restrict__ col,
                                                   const float* __restrict__ bneigh,
                                                   float* __restrict__ hout,
                                                   void* __restrict__ out2,
                                                   const int* __restrict__ flags, int N)
{
  int d = blockIdx.x * 4 + (threadIdx.x >> 6);
  if (d >= N) return;
  int lane = threadIdx.x & 63;
  int half = lane >> 5, f = lane & 31;
  int start = rowptr[d], end = rowptr[d + 1];
  float acc = 0.f;
  for (int e = start + half; e < end; e += 2)
    acc += t[(size_t)col[e] * 64 + 32 + f];
  acc += __shfl_down(acc, 32, 64);
  if (lane < 32) {
    int deg = end - start;
    float scale = 1.0f / (float)max(deg, 1);
    float v = fmaf(acc, scale, bneigh[f] + t[(size_t)d * 64 + f]);
    v = fmaxf(v, 0.f);
    hout[(size_t)d * 32 + f] = v;
    if (out2) {
      if (flags[0] != 0) ((ushort*)out2)[(size_t)d * 32 + f] = f2b(v);
      else               ((float*)out2)[(size_t)d * 32 + f] = v;
    }
  }
}

// ---------------------------------------------------------------------------
extern "C" void kernel_launch(void* const* d_in, const int* in_sizes, int n_in,
                              void* d_out, int out_size, void* d_ws, size_t ws_size,
                              hipStream_t stream)
{
  const int N = NN, E = NE;
  const void* x   = d_in[0];
  const int*  ei  = (const int*)d_in[1];

  char* p = (char*)d_ws;
  auto alloc = [&](size_t bytes) -> void* {
    void* r = (void*)p;
    p += (bytes + 255) & ~(size_t)255;
    return r;
  };
  float* wc1  = (float*)alloc(64 * 64 * 4);
  float* bc1  = (float*)alloc(64 * 4);
  float* wc2  = (float*)alloc(32 * 64 * 4);
  float* bc2  = (float*)alloc(64 * 4);
  float* wof  = (float*)alloc(32 * 40 * 4);
  float* bof  = (float*)alloc(40 * 4);
  float* bn1f = (float*)alloc(32 * 4);
  float* bn2f = (float*)alloc(32 * 4);
  int*   flags = (int*)alloc(8);
  int*   deg  = (int*)alloc((size_t)N * 4);
  int*   rowptr = (int*)alloc(((size_t)N + 1) * 4);
  int*   cursor = (int*)alloc((size_t)N * 4);
  int*   bsum = (int*)alloc(512 * 4);
  int*   col  = (int*)alloc((size_t)E * 4);
  float* tbuf = (float*)alloc((size_t)N * 64 * 4); // t1 / t2 (aliased)
  float* hbuf = (float*)alloc((size_t)N * 32 * 4); // h1 / h2 (aliased)

  const int NB = (N + 1023) / 1024; // 98

  prep_k<<<1, 256, 0, stream>>>((const uint*)x, ei,
                                d_in[2], d_in[3], d_in[4], d_in[5],
                                d_in[6], d_in[7], d_in[8], d_in[9],
                                d_in[10], d_in[11],
                                wc1, bc1, wc2, bc2, wof, bof, bn1f, bn2f, flags);
  hipMemsetAsync(deg, 0, (size_t)N * 4, stream);
  // 2048 blocks = 8 XCD ranges x 256 block-groups
  count_k<<<2048, 256, 0, stream>>>(ei, deg, flags, E);
  scan_partials_k<<<NB, 256, 0, stream>>>(deg, bsum, N);
  scan_bsum_k<<<1, 128, 0, stream>>>(bsum, NB);
  scan_apply_k<<<NB, 256, 0, stream>>>(deg, bsum, rowptr, cursor, N, E);
  fill_k<<<2048, 256, 0, stream>>>(ei, cursor, col, flags, E);

  // Layer 1: t1 = [x@Ws1+bs1 | x@Wn1], aggregate -> h1
  transform_k<64, 64, 32, true, false><<<(N + 255) / 256, 256, 0, stream>>>(
      x, wc1, bc1, tbuf, flags, 0LL, N);
  aggregate_k<<<(N + 3) / 4, 256, 0, stream>>>(tbuf, rowptr, col, bn1f, hbuf,
                                               (void*)nullptr, flags, N);

  // Layer 2: t2 = [h1@Ws2+bs2 | h1@Wn2], aggregate -> h2 (+x32 output)
  transform_k<32, 64, 64, false, false><<<(N + 255) / 256, 256, 0, stream>>>(
      hbuf, wc2, bc2, tbuf, flags, 0LL, N);
  aggregate_k<<<(N + 3) / 4, 256, 0, stream>>>(tbuf, rowptr, col, bn2f, hbuf,
                                               d_out, flags, N);

  // Output head: logits = h2@Wo + bo -> d_out at element offset N*32
  transform_k<32, 40, 40, false, true><<<(N + 255) / 256, 256, 0, stream>>>(
      hbuf, wof, bof, d_out, flags, (long long)N * 32, N);
}

// Round 5
// 417.343 us; speedup vs baseline: 1.3294x; 1.1923x over previous
//
#include <hip/hip_runtime.h>

// Problem constants (fixed by reference setup_inputs)
#define NN 100000
#define NE 1600000
#define NPR 12500  // nodes per XCD range (NN/8)

typedef unsigned int uint;
typedef unsigned short ushort;
typedef __fp16 fp16x2 __attribute__((ext_vector_type(2)));

__device__ __forceinline__ float blo(uint u){ return __uint_as_float(u << 16); }
__device__ __forceinline__ float bhi(uint u){ return __uint_as_float(u & 0xffff0000u); }
__device__ __forceinline__ float b2f(ushort u){ return __uint_as_float(((uint)u) << 16); }
__device__ __forceinline__ ushort f2b(float f){
  uint u = __float_as_uint(f);
  uint r = (u + 0x7fffu + ((u >> 16) & 1u)) >> 16;
  return (ushort)r;
}
__device__ __forceinline__ uint packh2(float a, float b){
  union { fp16x2 h; uint u; } c; c.h = __builtin_amdgcn_cvt_pkrtz(a, b); return c.u;
}
__device__ __forceinline__ float h2lo(uint u){
  union { uint u; fp16x2 h; } c; c.u = u; return (float)c.h.x;
}
__device__ __forceinline__ float h2hi(uint u){
  union { uint u; fp16x2 h; } c; c.u = u; return (float)c.h.y;
}
// load float element i from a buffer that is bf16 (isb) or f32
__device__ __forceinline__ float ldf(const void* p, int i, bool isb){
  return isb ? b2f(((const ushort*)p)[i]) : ((const float*)p)[i];
}

// ---------------------------------------------------------------------------
// prep: probe dtypes, convert weights to f32 combined tables
// flags[0] = 1 if float tensors are bf16, 0 if f32
// flags[1] = 1 if edge_index buffer is int64-layout, 0 if int32
// ---------------------------------------------------------------------------
__global__ void prep_k(const uint* __restrict__ xw,  const int* __restrict__ ei,
                       const void* __restrict__ Ws1, const void* __restrict__ bs1,
                       const void* __restrict__ Wn1, const void* __restrict__ bn1,
                       const void* __restrict__ Ws2, const void* __restrict__ bs2,
                       const void* __restrict__ Wn2, const void* __restrict__ bn2,
                       const void* __restrict__ Wo,  const void* __restrict__ bo,
                       float* __restrict__ wc1, float* __restrict__ bc1,
                       float* __restrict__ wc2, float* __restrict__ bc2,
                       float* __restrict__ wof, float* __restrict__ bof,
                       float* __restrict__ bn1f, float* __restrict__ bn2f,
                       int* __restrict__ flags)
{
  int t = threadIdx.x; // one block, 256 threads
  __shared__ int nz, bcnt;
  __shared__ int s_isb, s_ei64;
  if (t == 0) { nz = 0; bcnt = 0; }
  __syncthreads();

  // --- edge layout probe: int64 little-endian => every odd int32 word is 0
  int hiw = ei[2 * t + 1];
  if (hiw != 0) atomicOr(&nz, 1);

  // --- float dtype probe: bits[14:7] of each uint32 word are the low
  // element's bf16 exponent field if packed-bf16 (concentrated ~[96,144]);
  // uniform-random mantissa bits if f32.
  uint u = xw[t];
  uint le = (u >> 7) & 0xFFu;
  if (le == 0u || (le >= 96u && le <= 144u)) atomicAdd(&bcnt, 1);
  __syncthreads();
  if (t == 0) {
    s_ei64 = (nz == 0) ? 1 : 0;
    s_isb  = (bcnt >= 240) ? 1 : 0;
    flags[0] = s_isb;
    flags[1] = s_ei64;
  }
  __syncthreads();
  bool isb = (s_isb != 0);

  for (int i = t; i < 64 * 64; i += 256) {
    int f = i >> 6, j = i & 63;
    wc1[i] = (j < 32) ? ldf(Ws1, f * 32 + j, isb) : ldf(Wn1, f * 32 + (j - 32), isb);
  }
  for (int i = t; i < 64; i += 256) bc1[i] = (i < 32) ? ldf(bs1, i, isb) : 0.f;
  for (int i = t; i < 32 * 64; i += 256) {
    int f = i >> 6, j = i & 63;
    wc2[i] = (j < 32) ? ldf(Ws2, f * 32 + j, isb) : ldf(Wn2, f * 32 + (j - 32), isb);
  }
  for (int i = t; i < 64; i += 256) bc2[i] = (i < 32) ? ldf(bs2, i, isb) : 0.f;
  for (int i = t; i < 32 * 40; i += 256) wof[i] = ldf(Wo, i, isb);
  for (int i = t; i < 40; i += 256) bof[i] = ldf(bo, i, isb);
  for (int i = t; i < 32; i += 256) bn1f[i] = ldf(bn1, i, isb);
  for (int i = t; i < 32; i += 256) bn2f[i] = ldf(bn2, i, isb);
}

// ---------------------------------------------------------------------------
// CSR build — XCD-partitioned scatter (blockIdx%8 -> XCD range of 12.5K dsts;
// cursor+col slices stay L2-resident per XCD).
// ---------------------------------------------------------------------------
__global__ __launch_bounds__(256) void count_k(const int* __restrict__ ei,
                                               int* __restrict__ deg,
                                               const int* __restrict__ flags, int E)
{
  int r = blockIdx.x & 7;
  int grp = blockIdx.x >> 3;
  int nb = gridDim.x >> 3;
  int m = flags[1];
  int lo = r * NPR, hi = lo + NPR;
  for (int e = grp * 256 + threadIdx.x; e < E; e += nb * 256) {
    int d = m ? ei[2 * (E + e)] : ei[E + e];
    if (d >= lo && d < hi) atomicAdd(&deg[d], 1);
  }
}

__global__ void scan_partials_k(const int* __restrict__ deg, int* __restrict__ bsum, int N)
{
  __shared__ int sm[256];
  int b = blockIdx.x, t = threadIdx.x;
  int base = b * 1024 + t * 4;
  int s = 0;
#pragma unroll
  for (int k = 0; k < 4; k++) { int i = base + k; if (i < N) s += deg[i]; }
  sm[t] = s;
  __syncthreads();
  for (int off = 128; off > 0; off >>= 1) {
    if (t < off) sm[t] += sm[t + off];
    __syncthreads();
  }
  if (t == 0) bsum[b] = sm[0];
}

__global__ void scan_bsum_k(int* __restrict__ bsum, int NB)
{
  __shared__ int sm[128];
  int t = threadIdx.x;
  int orig = (t < NB) ? bsum[t] : 0;
  sm[t] = orig;
  __syncthreads();
  for (int off = 1; off < 128; off <<= 1) {
    int v = (t >= off) ? sm[t - off] : 0;
    __syncthreads();
    sm[t] += v;
    __syncthreads();
  }
  if (t < NB) bsum[t] = sm[t] - orig; // exclusive
}

__global__ void scan_apply_k(const int* __restrict__ deg, const int* __restrict__ bsum,
                             int* __restrict__ rowptr, int* __restrict__ cursor, int N, int E)
{
  __shared__ int sm[256];
  int b = blockIdx.x, t = threadIdx.x;
  int base = b * 1024 + t * 4;
  int v[4]; int s = 0;
#pragma unroll
  for (int k = 0; k < 4; k++) { int i = base + k; v[k] = (i < N) ? deg[i] : 0; s += v[k]; }
  sm[t] = s;
  __syncthreads();
  for (int off = 1; off < 256; off <<= 1) {
    int x = (t >= off) ? sm[t - off] : 0;
    __syncthreads();
    sm[t] += x;
    __syncthreads();
  }
  int excl = sm[t] - s + bsum[b];
#pragma unroll
  for (int k = 0; k < 4; k++) {
    int i = base + k;
    if (i < N) { rowptr[i] = excl; cursor[i] = excl; }
    excl += v[k];
  }
  if (b == 0 && t == 0) rowptr[N] = E;
}

__global__ __launch_bounds__(256) void fill_k(const int* __restrict__ ei,
                                              int* __restrict__ cursor,
                                              int* __restrict__ col,
                                              const int* __restrict__ flags, int E)
{
  int r = blockIdx.x & 7;
  int grp = blockIdx.x >> 3;
  int nb = gridDim.x >> 3;
  int m = flags[1];
  int lo = r * NPR, hi = lo + NPR;
  for (int e = grp * 256 + threadIdx.x; e < E; e += nb * 256) {
    int d = m ? ei[2 * (E + e)] : ei[E + e];
    if (d >= lo && d < hi) {
      int s = m ? ei[2 * e] : ei[e];
      int p = atomicAdd(&cursor[d], 1);
      col[p] = s;
    }
  }
}

// ---------------------------------------------------------------------------
// Split transform: thread-per-node. Cols 0..31 (self+bias) -> tself f32;
// cols 32..63 (neigh) -> tneigh packed f16 pairs (16 uints = 64B rows, so the
// whole gather table is 6.4MB -> mostly L2-resident during aggregation).
// ---------------------------------------------------------------------------
template <int IN, bool XDYN>
__global__ __launch_bounds__(256) void transform_split_k(const void* __restrict__ xin,
                                                         const float* __restrict__ W,
                                                         const float* __restrict__ bias,
                                                         float* __restrict__ tself,
                                                         uint* __restrict__ tneigh,
                                                         const int* __restrict__ flags, int N)
{
  int n = blockIdx.x * 256 + threadIdx.x;
  if (n >= N) return;
  bool isb = XDYN ? (flags[0] != 0) : false;
  float xr[IN];
  if (XDYN && isb) {
    const uint4* p = (const uint4*)((const ushort*)xin + (size_t)n * IN);
#pragma unroll
    for (int k = 0; k < IN / 8; k++) {
      uint4 v = p[k];
      xr[8 * k + 0] = blo(v.x); xr[8 * k + 1] = bhi(v.x);
      xr[8 * k + 2] = blo(v.y); xr[8 * k + 3] = bhi(v.y);
      xr[8 * k + 4] = blo(v.z); xr[8 * k + 5] = bhi(v.z);
      xr[8 * k + 6] = blo(v.w); xr[8 * k + 7] = bhi(v.w);
    }
  } else {
    const float4* p = (const float4*)((const float*)xin + (size_t)n * IN);
#pragma unroll
    for (int k = 0; k < IN / 4; k++) {
      float4 v = p[k];
      xr[4 * k + 0] = v.x; xr[4 * k + 1] = v.y; xr[4 * k + 2] = v.z; xr[4 * k + 3] = v.w;
    }
  }
#pragma unroll 1
  for (int j0 = 0; j0 < 64; j0 += 32) {
    float acc[32];
#pragma unroll
    for (int jj = 0; jj < 32; jj++) acc[jj] = bias[j0 + jj];
#pragma unroll 8
    for (int f = 0; f < IN; f++) {
      float xv = xr[f];
#pragma unroll
      for (int jj = 0; jj < 32; jj++)
        acc[jj] = fmaf(xv, W[f * 64 + j0 + jj], acc[jj]);
    }
    if (j0 == 0) {
      float* o = tself + (size_t)n * 32;
#pragma unroll
      for (int q = 0; q < 8; q++)
        ((float4*)o)[q] = make_float4(acc[4 * q], acc[4 * q + 1], acc[4 * q + 2], acc[4 * q + 3]);
    } else {
      uint* o = tneigh + (size_t)n * 16;
#pragma unroll
      for (int q = 0; q < 4; q++) {
        uint4 v;
        v.x = packh2(acc[8 * q + 0], acc[8 * q + 1]);
        v.y = packh2(acc[8 * q + 2], acc[8 * q + 3]);
        v.z = packh2(acc[8 * q + 4], acc[8 * q + 5]);
        v.w = packh2(acc[8 * q + 6], acc[8 * q + 7]);
        ((uint4*)o)[q] = v;
      }
    }
  }
}

// ---------------------------------------------------------------------------
// Generic transform (output head): thread-per-node, f32 in, bf16/f32 out.
// ---------------------------------------------------------------------------
template <int IN, int OUT, int CHUNK>
__global__ __launch_bounds__(256) void transform_k(const float* __restrict__ xin,
                                                   const float* __restrict__ W,
                                                   const float* __restrict__ bias,
                                                   void* __restrict__ xout,
                                                   const int* __restrict__ flags,
                                                   long long eoff, int N)
{
  int n = blockIdx.x * 256 + threadIdx.x;
  if (n >= N) return;
  bool isb = (flags[0] != 0);
  float xr[IN];
  const float4* p = (const float4*)(xin + (size_t)n * IN);
#pragma unroll
  for (int k = 0; k < IN / 4; k++) {
    float4 v = p[k];
    xr[4 * k + 0] = v.x; xr[4 * k + 1] = v.y; xr[4 * k + 2] = v.z; xr[4 * k + 3] = v.w;
  }
#pragma unroll 1
  for (int j0 = 0; j0 < OUT; j0 += CHUNK) {
    float acc[CHUNK];
#pragma unroll
    for (int jj = 0; jj < CHUNK; jj++) acc[jj] = bias[j0 + jj];
#pragma unroll 8
    for (int f = 0; f < IN; f++) {
      float xv = xr[f];
#pragma unroll
      for (int jj = 0; jj < CHUNK; jj++)
        acc[jj] = fmaf(xv, W[f * OUT + j0 + jj], acc[jj]);
    }
    if (isb) {
      uint* o = (uint*)((ushort*)xout + eoff + (size_t)n * OUT + j0);
#pragma unroll
      for (int q = 0; q < CHUNK / 2; q++)
        o[q] = (uint)f2b(acc[2 * q]) | ((uint)f2b(acc[2 * q + 1]) << 16);
    } else {
      float* o = (float*)xout + eoff + (size_t)n * OUT + j0;
#pragma unroll
      for (int q = 0; q < CHUNK / 4; q++)
        ((float4*)o)[q] = make_float4(acc[4 * q], acc[4 * q + 1], acc[4 * q + 2], acc[4 * q + 3]);
    }
  }
}

// ---------------------------------------------------------------------------
// Aggregation v2: wave = node. Lane = 16*slot + f2: 4 neighbor rows in
// parallel (16 lanes x 1 uint = 64B row each), x2 manual unroll = 8 gathers
// in flight. col indices pre-loaded coalesced, broadcast via shfl (no
// dependent index load inside the gather loop). Reduce across slots with 2
// shuffles. Epilogue on lanes 0..15 (2 feats each).
// ---------------------------------------------------------------------------
__global__ __launch_bounds__(256) void aggregate_k(const float* __restrict__ tself,
                                                   const uint* __restrict__ tneigh,
                                                   const int* __restrict__ rowptr,
                                                   const int* __restrict__ col,
                                                   const float* __restrict__ bneigh,
                                                   float* __restrict__ hout,
                                                   void* __restrict__ out2,
                                                   const int* __restrict__ flags, int N)
{
  int d = blockIdx.x * 4 + (threadIdx.x >> 6);
  if (d >= N) return;
  int lane = threadIdx.x & 63;
  int slot = lane >> 4, f2 = lane & 15;
  int start = rowptr[d], end = rowptr[d + 1];
  int deg = end - start;
  float a0 = 0.f, a1 = 0.f;
  for (int base = start; base < end; base += 64) {
    int cnt = min(64, end - base);
    int ce = (lane < cnt) ? col[base + lane] : 0;
#pragma unroll 1
    for (int j = 0; j < cnt; j += 8) {
      int k0 = j + slot, k1 = j + 4 + slot;
      int i0 = __shfl(ce, k0, 64);
      int i1 = __shfl(ce, k1, 64);
      if (k0 < cnt) { uint u = tneigh[(size_t)i0 * 16 + f2]; a0 += h2lo(u); a1 += h2hi(u); }
      if (k1 < cnt) { uint u = tneigh[(size_t)i1 * 16 + f2]; a0 += h2lo(u); a1 += h2hi(u); }
    }
  }
  a0 += __shfl_down(a0, 32, 64); a1 += __shfl_down(a1, 32, 64);
  a0 += __shfl_down(a0, 16, 64); a1 += __shfl_down(a1, 16, 64);
  if (lane < 16) {
    float scale = 1.0f / (float)max(deg, 1);
    float2 self = ((const float2*)(tself + (size_t)d * 32))[f2];
    float v0 = fmaxf(fmaf(a0, scale, bneigh[2 * f2]     + self.x), 0.f);
    float v1 = fmaxf(fmaf(a1, scale, bneigh[2 * f2 + 1] + self.y), 0.f);
    ((float2*)(hout + (size_t)d * 32))[f2] = make_float2(v0, v1);
    if (out2) {
      if (flags[0] != 0)
        ((uint*)out2)[(size_t)d * 16 + f2] = (uint)f2b(v0) | ((uint)f2b(v1) << 16);
      else
        ((float2*)out2)[(size_t)d * 16 + f2] = make_float2(v0, v1);
    }
  }
}

// ---------------------------------------------------------------------------
extern "C" void kernel_launch(void* const* d_in, const int* in_sizes, int n_in,
                              void* d_out, int out_size, void* d_ws, size_t ws_size,
                              hipStream_t stream)
{
  const int N = NN, E = NE;
  const void* x   = d_in[0];
  const int*  ei  = (const int*)d_in[1];

  char* p = (char*)d_ws;
  auto alloc = [&](size_t bytes) -> void* {
    void* r = (void*)p;
    p += (bytes + 255) & ~(size_t)255;
    return r;
  };
  float* wc1  = (float*)alloc(64 * 64 * 4);
  float* bc1  = (float*)alloc(64 * 4);
  float* wc2  = (float*)alloc(32 * 64 * 4);
  float* bc2  = (float*)alloc(64 * 4);
  float* wof  = (float*)alloc(32 * 40 * 4);
  float* bof  = (float*)alloc(40 * 4);
  float* bn1f = (float*)alloc(32 * 4);
  float* bn2f = (float*)alloc(32 * 4);
  int*   flags = (int*)alloc(8);
  int*   deg  = (int*)alloc((size_t)N * 4);
  int*   rowptr = (int*)alloc(((size_t)N + 1) * 4);
  int*   cursor = (int*)alloc((size_t)N * 4);
  int*   bsum = (int*)alloc(512 * 4);
  int*   col  = (int*)alloc((size_t)E * 4);
  float* tself  = (float*)alloc((size_t)N * 32 * 4); // f32 self half
  uint*  tneigh = (uint*)alloc((size_t)N * 16 * 4);  // f16-packed neigh half
  float* hbuf = (float*)alloc((size_t)N * 32 * 4);   // h1 / h2 (aliased)

  const int NB = (N + 1023) / 1024; // 98

  prep_k<<<1, 256, 0, stream>>>((const uint*)x, ei,
                                d_in[2], d_in[3], d_in[4], d_in[5],
                                d_in[6], d_in[7], d_in[8], d_in[9],
                                d_in[10], d_in[11],
                                wc1, bc1, wc2, bc2, wof, bof, bn1f, bn2f, flags);
  (void)hipMemsetAsync(deg, 0, (size_t)N * 4, stream);
  // 2048 blocks = 8 XCD ranges x 256 block-groups
  count_k<<<2048, 256, 0, stream>>>(ei, deg, flags, E);
  scan_partials_k<<<NB, 256, 0, stream>>>(deg, bsum, N);
  scan_bsum_k<<<1, 128, 0, stream>>>(bsum, NB);
  scan_apply_k<<<NB, 256, 0, stream>>>(deg, bsum, rowptr, cursor, N, E);
  fill_k<<<2048, 256, 0, stream>>>(ei, cursor, col, flags, E);

  // Layer 1: [x@Ws1+bs1 | x@Wn1] -> tself/tneigh, aggregate -> h1
  transform_split_k<64, true><<<(N + 255) / 256, 256, 0, stream>>>(
      x, wc1, bc1, tself, tneigh, flags, N);
  aggregate_k<<<(N + 3) / 4, 256, 0, stream>>>(tself, tneigh, rowptr, col, bn1f,
                                               hbuf, (void*)nullptr, flags, N);

  // Layer 2: [h1@Ws2+bs2 | h1@Wn2] -> tself/tneigh, aggregate -> h2 (+x32 out)
  transform_split_k<32, false><<<(N + 255) / 256, 256, 0, stream>>>(
      hbuf, wc2, bc2, tself, tneigh, flags, N);
  aggregate_k<<<(N + 3) / 4, 256, 0, stream>>>(tself, tneigh, rowptr, col, bn2f,
                                               hbuf, d_out, flags, N);

  // Output head: logits = h2@Wo + bo -> d_out at element offset N*32
  transform_k<32, 40, 40><<<(N + 255) / 256, 256, 0, stream>>>(
      hbuf, wof, bof, d_out, flags, (long long)N * 32, N);
}